// Round 17
// baseline (410.563 us; speedup 1.0000x reference)
//
#include <hip/hip_runtime.h>
#include <hip/hip_bf16.h>

// ---------------- problem constants ----------------
constexpr int U_  = 51200;
constexpr int I_  = 25600;
constexpr int E_  = 1000000;
constexpr int EP_ = 100000;
constexpr int CB_ = 256;                 // contrastive chunk size
constexpr int NCHUNK_ = U_ / CB_;        // 200
constexpr size_t UD_ = (size_t)U_ * 64;
constexpr size_t ID_ = (size_t)I_ * 64;
constexpr int NBK_ = 200;                // buckets per side
constexpr int CAP_ = 8192;               // record slots per bucket
constexpr int TILE_ = 4096;              // edges per Phase-A block
constexpr int NBA_ = (E_ + TILE_ - 1) / TILE_;  // 245
constexpr int NANC_ = U_ / 16;           // 3200 anchor blocks
constexpr int NCVT_ = (int)((UD_ + ID_) / 512);  // 9600 convert blocks

// fp8 scaling
constexpr float SCALE_E_  = 16.f;   // raw embeddings ~0.1
constexpr float ISCALE_E_ = 1.f / 16.f;
constexpr float SCALE_1_  = 64.f;   // layer-1 aggregates ~0.02
constexpr float ISCALE_1_ = 1.f / 64.f;

// ---------------- workspace layout (4-byte element offsets) ----------------
constexpr size_t OFF_LOSS  = 0;
constexpr size_t OFF_FLAG  = 1;
constexpr size_t OFF_CURU  = 8;                      // 200 ints
constexpr size_t OFF_CURI  = 208;                    // 200 ints
constexpr size_t MEMSET_BYTES = 408 * 4;
constexpr size_t OFF_VEC   = 448;                    // 192 floats
constexpr size_t OFF_BBU   = 640;                    // 201 ints
constexpr size_t OFF_BBI   = 848;                    // 201 ints
constexpr size_t OFF_ROWU  = 1088;                   // U_+1
constexpr size_t OFF_ROWI  = ((OFF_ROWU + U_ + 1 + 63) / 64) * 64;   // I_+1
constexpr size_t OFF_CSRU  = ((OFF_ROWI + I_ + 1 + 63) / 64) * 64;   // E_
constexpr size_t OFF_CSRI  = OFF_CSRU + E_;          // E_
constexpr size_t OFF_U1    = ((OFF_CSRI + E_ + 63) / 64) * 64;       // UD_ (bf16)
constexpr size_t OFF_I1    = OFF_U1 + UD_;
constexpr size_t OFF_HU    = OFF_I1 + ID_;           // bufU aliases
constexpr size_t OFF_HI    = OFF_HU + UD_;           // bufI aliases
constexpr size_t OFF_ANC   = OFF_HI + ID_;
constexpr size_t OFF_UE8   = OFF_ANC + UD_;          // UD_ bytes (fp8)
constexpr size_t OFF_IE8   = OFF_UE8 + UD_ / 4;
constexpr size_t OFF_U18   = OFF_IE8 + ID_ / 4;
constexpr size_t OFF_I18   = OFF_U18 + UD_ / 4;
constexpr size_t OFF_HUB   = OFF_I18 + ID_ / 4;      // UD_ bf16 (hu copy)
constexpr size_t OFF_HIB   = OFF_HUB + UD_ / 2;      // ID_ bf16 (hi copy)
// total ≈ 70.5 MB

#define DEVI static __device__ __forceinline__

typedef _Float16 h2v __attribute__((ext_vector_type(2)));
typedef _Float16 f16x8 __attribute__((ext_vector_type(8)));
typedef float floatx4 __attribute__((ext_vector_type(4)));

DEVI float b2f(__hip_bfloat16 x) { return __bfloat162float(x); }

DEVI float ldf(const void* p, size_t i, int isf32) {
  if (isf32) return ((const float*)p)[i];
  return b2f(((const __hip_bfloat16*)p)[i]);
}

DEVI float frcp(float x) { return __builtin_amdgcn_rcpf(x); }

DEVI float fexp2(float x) {
#if __has_builtin(__builtin_amdgcn_exp2f)
  return __builtin_amdgcn_exp2f(x);
#else
  return exp2f(x);
#endif
}

// fp8 e4m3 (OCP) decode/encode
DEVI float fp8_dec(unsigned v) {
#if __has_builtin(__builtin_amdgcn_cvt_f32_fp8)
  return __builtin_amdgcn_cvt_f32_fp8(v, 0);
#else
  unsigned b = v & 0xFF;
  if (!(b & 0x78)) return 0.f;
  unsigned short h = (unsigned short)(((b & 0x80) << 8) | (((b & 0x7f) + (8 << 3)) << 7));
  _Float16 hf; __builtin_memcpy(&hf, &h, 2);
  return (float)hf;
#endif
}
DEVI unsigned fp8_enc_pk(float a, float b) {
#if __has_builtin(__builtin_amdgcn_cvt_pk_fp8_f32)
  return __builtin_amdgcn_cvt_pk_fp8_f32(a, b, 0u, false);
#else
  auto enc1 = [](float f) -> unsigned {
    _Float16 hf = (_Float16)f; unsigned short hb; __builtin_memcpy(&hb, &hf, 2);
    int s = hb >> 15, e = (hb >> 10) & 31, m = hb & 1023;
    int e8 = e - 15 + 7;
    int m3 = (m + ((1 << 6) + ((m >> 7) & 1))) >> 7;
    if (m3 > 7) { m3 = 0; e8++; }
    if (e8 <= 0) return (unsigned)(s << 7);
    if (e8 > 15) { e8 = 15; m3 = 6; }
    return (unsigned)((s << 7) | (e8 << 3) | m3);
  };
  return enc1(a) | (enc1(b) << 8);
#endif
}

DEVI int waveInclScan(int v, int lane) {
  #pragma unroll
  for (int off = 1; off < 64; off <<= 1) {
    int t = __shfl_up(v, off, 64);
    if (lane >= off) v += t;
  }
  return v;
}

// ---------------- 0. prep ----------------
__global__ void prep_kernel(const unsigned short* __restrict__ ueu,
                            const void* __restrict__ W, const void* __restrict__ a,
                            const void* __restrict__ WU, const void* __restrict__ aU,
                            float* __restrict__ vecs, float* __restrict__ flag) {
  int cnt = 0;
  for (int i = 0; i < 256; i++) {
    int e = (ueu[i] >> 7) & 0xFF;
    if (e >= 130) cnt++;
  }
  int isf32 = (cnt >= 8);
  if (threadIdx.x == 0) *flag = isf32 ? 1.0f : 0.0f;
  int d = threadIdx.x;
  float s = 0.f, t1 = 0.f, t2 = 0.f;
  for (int e = 0; e < 64; e++) {
    s += ldf(W, d * 64 + e, isf32) * ldf(a, e, isf32);
    float wue = ldf(WU, d * 64 + e, isf32);
    t1 += wue * ldf(aU, e, isf32);
    t2 += wue * ldf(aU, 64 + e, isf32);
  }
  vecs[d] = s;
  vecs[64 + d] = t1;
  vecs[128 + d] = t2;
}

// ---------------- 0b. fp8 convert of embedding tables (before fusedA) ----------
__global__ __launch_bounds__(256) void convert_kernel(
    const void* __restrict__ ue, const void* __restrict__ ie,
    unsigned char* __restrict__ ue8, unsigned char* __restrict__ ie8,
    const float* __restrict__ flag) {
  int isf32 = *flag > 0.5f;
  size_t t = (size_t)blockIdx.x * 256 + threadIdx.x;   // element-pair index
  float a, b; unsigned short* dst; size_t o;
  if (t < UD_ / 2) {
    a = ldf(ue, 2 * t, isf32); b = ldf(ue, 2 * t + 1, isf32);
    dst = (unsigned short*)ue8; o = t;
  } else {
    size_t s = t - UD_ / 2;
    a = ldf(ie, 2 * s, isf32); b = ldf(ie, 2 * s + 1, isf32);
    dst = (unsigned short*)ie8; o = s;
  }
  unsigned p = fp8_enc_pk(a * SCALE_E_, b * SCALE_E_);
  dst[o] = (unsigned short)(p & 0xFFFF);
}

// ---------------- fused A: bucketA (blocks 0..244) + anchor (rest) -------------
struct BktSmem {
  int histU[NBK_], histI[NBK_];
  int loffU[NBK_ + 1], loffI[NBK_ + 1];
  int cbU[NBK_], cbI[NBK_];
  int lcU[NBK_], lcI[NBK_];
  int wsU[4], wsI[4];
  unsigned recsU[TILE_], recsI[TILE_];
};
constexpr int WS_ = 72;
struct AncSmem {
  _Float16 WUt[64 * WS_];
  _Float16 mixS[16 * WS_];
  float invSe[16];
  int nbrS[128];
};
constexpr size_t FSA_SMEM = sizeof(BktSmem) > sizeof(AncSmem) ? sizeof(BktSmem) : sizeof(AncSmem);

DEVI void bucketA_body(char* smemRaw, int blk,
    const int* __restrict__ rs, const int* __restrict__ rd,
    unsigned* __restrict__ bufU, unsigned* __restrict__ bufI,
    int* __restrict__ curU, int* __restrict__ curI) {
  BktSmem& S = *(BktSmem*)smemRaw;
  int tid = threadIdx.x;
  int base = blk * TILE_;
  for (int i = tid; i < NBK_; i += 256) { S.histU[i] = 0; S.histI[i] = 0; }
  __syncthreads();
  int ss[16], dd[16];
  #pragma unroll
  for (int t = 0; t < 16; t++) {
    int e = base + t * 256 + tid;
    bool v = e < E_;
    ss[t] = v ? rs[e] : -1;
    dd[t] = v ? rd[e] : 0;
    if (v) {
      atomicAdd(&S.histU[ss[t] >> 8], 1);
      atomicAdd(&S.histI[dd[t] >> 7], 1);
    }
  }
  __syncthreads();
  if (tid < NBK_) {
    int cU = S.histU[tid];
    S.cbU[tid] = tid * CAP_ + (cU ? atomicAdd(&curU[tid], cU) : 0);
    int cI = S.histI[tid];
    S.cbI[tid] = tid * CAP_ + (cI ? atomicAdd(&curI[tid], cI) : 0);
  }
  int lane = tid & 63, wv = tid >> 6;
  int cvU = (tid < NBK_) ? S.histU[tid] : 0;
  int cvI = (tid < NBK_) ? S.histI[tid] : 0;
  int inU = waveInclScan(cvU, lane);
  int inI = waveInclScan(cvI, lane);
  if (lane == 63) { S.wsU[wv] = inU; S.wsI[wv] = inI; }
  __syncthreads();
  int woU = 0, woI = 0;
  for (int w = 0; w < wv; w++) { woU += S.wsU[w]; woI += S.wsI[w]; }
  if (tid < NBK_) {
    S.loffU[tid] = woU + inU - cvU;
    S.loffI[tid] = woI + inI - cvI;
  }
  if (tid == NBK_ - 1) {
    S.loffU[NBK_] = woU + inU;
    S.loffI[NBK_] = woI + inI;
  }
  __syncthreads();
  if (tid < NBK_) { S.lcU[tid] = S.loffU[tid]; S.lcI[tid] = S.loffI[tid]; }
  __syncthreads();
  #pragma unroll
  for (int t = 0; t < 16; t++) {
    if (ss[t] >= 0) {
      int b = ss[t] >> 8;
      int p = atomicAdd(&S.lcU[b], 1);
      S.recsU[p] = ((unsigned)(ss[t] & 255) << 17) | (unsigned)dd[t];
      b = dd[t] >> 7;
      p = atomicAdd(&S.lcI[b], 1);
      S.recsI[p] = ((unsigned)(dd[t] & 127) << 17) | (unsigned)ss[t];
    }
  }
  __syncthreads();
  int totU = S.loffU[NBK_];
  for (int p = tid; p < totU; p += 256) {
    int lo = 0, hi = NBK_;
    while (hi - lo > 1) { int mid = (lo + hi) >> 1; if (S.loffU[mid] <= p) lo = mid; else hi = mid; }
    bufU[S.cbU[lo] + (p - S.loffU[lo])] = S.recsU[p];
  }
  int totI = S.loffI[NBK_];
  for (int p = tid; p < totI; p += 256) {
    int lo = 0, hi = NBK_;
    while (hi - lo > 1) { int mid = (lo + hi) >> 1; if (S.loffI[mid] <= p) lo = mid; else hi = mid; }
    bufI[S.cbI[lo] + (p - S.loffI[lo])] = S.recsI[p];
  }
}

// anchor: gathers from fp8 ue8 table (L2-resident); descale folded into y/q.
DEVI void anchor_body(char* smemRaw, int blk,
    const unsigned char* __restrict__ ue8, const void* __restrict__ WU,
    const void* __restrict__ cw, const float* __restrict__ vecs,
    const int* __restrict__ nbr, float* __restrict__ out, int isf32) {
  AncSmem& S = *(AncSmem*)smemRaw;
  int tid = threadIdx.x;
  int wv = tid >> 6, lane = tid & 63;
  int ublk = blk * 16;

  #pragma unroll
  for (int it = 0; it < 16; it++) {
    int k = it * 4 + wv;
    S.WUt[lane * WS_ + k] = (_Float16)ldf(WU, (size_t)k * 64 + lane, isf32);
  }
  if (tid < 128) S.nbrS[tid] = nbr[ublk * 8 + tid];
  __syncthreads();

  float cw0 = ldf(cw, (0 * 64 + lane) * 2, isf32);
  float w1r = ldf(cw, (1 * 64 + lane) * 2, isf32), w1i = ldf(cw, (1 * 64 + lane) * 2 + 1, isf32);
  float w2r = ldf(cw, (2 * 64 + lane) * 2, isf32), w2i = ldf(cw, (2 * 64 + lane) * 2 + 1, isf32);
  float w3r = ldf(cw, (3 * 64 + lane) * 2, isf32), w3i = ldf(cw, (3 * 64 + lane) * 2 + 1, isf32);
  float cw4 = ldf(cw, (4 * 64 + lane) * 2, isf32);
  float v1 = vecs[64 + lane], v2 = vecs[128 + lane];
  const float c1 = 0.70710678118654752440f;
  const float YSC = 0.125f * ISCALE_E_;   // irfft 1/8 + fp8 descale

  float xc[8], xn[8];
  #pragma unroll
  for (int k = 0; k < 8; k++)
    xc[k] = fp8_dec(ue8[(size_t)S.nbrS[wv * 32 + k] * 64 + lane]);

  for (int u4 = 0; u4 < 4; u4++) {
    int uL = wv * 4 + u4;
    int u = ublk + uL;
    if (u4 < 3) {
      #pragma unroll
      for (int k = 0; k < 8; k++)
        xn[k] = fp8_dec(ue8[(size_t)S.nbrS[wv * 32 + (u4 + 1) * 8 + k] * 64 + lane]);
    }
    float sA = xc[1] - xc[3] - xc[5] + xc[7];
    float sB = xc[1] + xc[3] - xc[5] - xc[7];
    float ev = (xc[0] + xc[4]) + (xc[2] + xc[6]);
    float od = (xc[1] + xc[5]) + (xc[3] + xc[7]);
    float d04 = xc[0] - xc[4], d26 = xc[2] - xc[6];
    float X0r = ev + od;
    float X1r = d04 + c1 * sA;
    float X1i = -d26 - c1 * sB;
    float X2r = (xc[0] + xc[4]) - (xc[2] + xc[6]);
    float X2i = -(xc[1] - xc[3] + xc[5] - xc[7]);
    float X3r = d04 - c1 * sA;
    float X3i = d26 - c1 * sB;
    float X4r = ev - od;
    float Zr0 = X0r * cw0;
    float Zr1 = X1r * w1r - X1i * w1i, Zi1 = X1r * w1i + X1i * w1r;
    float Zr2 = X2r * w2r - X2i * w2i, Zi2 = X2r * w2i + X2i * w2r;
    float Zr3 = X3r * w3r - X3i * w3i, Zi3 = X3r * w3i + X3i * w3r;
    float Zr4 = X4r * cw4;
    float eP = Zr0 + Zr4, eM = Zr0 - Zr4;
    float t1 = c1 * (Zr1 - Zr3), t2 = c1 * (Zi1 + Zi3);
    float y[8];
    y[0] = eP + 2.f * (Zr1 + Zr2 + Zr3);
    y[1] = eM + 2.f * (t1 - t2 - Zi2);
    y[2] = eP + 2.f * (-Zi1 - Zr2 + Zi3);
    y[3] = eM + 2.f * (-t1 - t2 + Zi2);
    y[4] = eP + 2.f * (-Zr1 + Zr2 - Zr3);
    y[5] = eM + 2.f * (-t1 + t2 - Zi2);
    y[6] = eP + 2.f * (Zi1 - Zr2 - Zi3);
    y[7] = eM + 2.f * (t1 + t2 + Zi2);
    #pragma unroll
    for (int k = 0; k < 8; k++) y[k] *= YSC;

    float ek[8];
    #pragma unroll
    for (int k = 0; k < 8; k++) ek[k] = y[k] * v1;
    float q = fp8_dec(ue8[(size_t)u * 64 + lane]) * ISCALE_E_ * v2;
    #pragma unroll
    for (int off = 32; off; off >>= 1) {
      #pragma unroll
      for (int k = 0; k < 8; k++) ek[k] += __shfl_xor(ek[k], off, 64);
      q += __shfl_xor(q, off, 64);
    }
    float m = -1e30f;
    #pragma unroll
    for (int k = 0; k < 8; k++) {
      float v = ek[k] + q;
      v = v > 0.f ? v : 0.1f * v;  // LeakyReLU(0.1)
      ek[k] = v;
      m = fmaxf(m, v);
    }
    float se = 0.f, wexp[8];
    #pragma unroll
    for (int k = 0; k < 8; k++) { wexp[k] = __expf(ek[k] - m); se += wexp[k]; }
    float mix = 0.f;
    #pragma unroll
    for (int k = 0; k < 8; k++) mix += wexp[k] * y[k];
    S.mixS[uL * WS_ + lane] = (_Float16)mix;
    if (lane == 0) S.invSe[uL] = frcp(se);
    #pragma unroll
    for (int k = 0; k < 8; k++) xc[k] = xn[k];
  }
  __syncthreads();

  int n = lane & 15, qd = lane >> 4;
  f16x8 A0 = *(const f16x8*)&S.mixS[(lane & 15) * WS_ + qd * 8];
  f16x8 A1 = *(const f16x8*)&S.mixS[(lane & 15) * WS_ + 32 + qd * 8];
  f16x8 B0 = *(const f16x8*)&S.WUt[(wv * 16 + n) * WS_ + qd * 8];
  f16x8 B1 = *(const f16x8*)&S.WUt[(wv * 16 + n) * WS_ + 32 + qd * 8];
  const floatx4 zero = {0.f, 0.f, 0.f, 0.f};
  floatx4 acc = __builtin_amdgcn_mfma_f32_16x16x32_f16(A0, B0, zero, 0, 0, 0);
  acc = __builtin_amdgcn_mfma_f32_16x16x32_f16(A1, B1, acc, 0, 0, 0);
  #pragma unroll
  for (int r = 0; r < 4; r++) {
    int m = qd * 4 + r;
    out[(size_t)(ublk + m) * 64 + wv * 16 + n] = acc[r] * S.invSe[m];
  }
}

__global__ __launch_bounds__(256) void fusedA_kernel(
    const int* __restrict__ rs, const int* __restrict__ rd,
    unsigned* __restrict__ bufU, unsigned* __restrict__ bufI,
    int* __restrict__ curU, int* __restrict__ curI,
    const unsigned char* __restrict__ ue8, const void* __restrict__ WU,
    const void* __restrict__ cw, const float* __restrict__ vecs,
    const int* __restrict__ nbr, float* __restrict__ anc,
    const float* __restrict__ flag) {
  __shared__ __align__(16) char smem[FSA_SMEM];
  if (blockIdx.x < NBA_) {
    bucketA_body(smem, blockIdx.x, rs, rd, bufU, bufI, curU, curI);
  } else {
    anchor_body(smem, blockIdx.x - NBA_, ue8, WU, cw, vecs, nbr, anc, *flag > 0.5f);
  }
}

// ---------------- 1b. tiny scan ----------------
__global__ void scanBuckets_kernel(const int* __restrict__ curU,
                                   const int* __restrict__ curI,
                                   int* __restrict__ bbU, int* __restrict__ bbI,
                                   int* __restrict__ rowU, int* __restrict__ rowI) {
  if (threadIdx.x == 0) {
    int run = 0;
    for (int i = 0; i < NBK_; i++) { bbU[i] = run; run += curU[i]; }
    bbU[NBK_] = run;
    run = 0;
    for (int i = 0; i < NBK_; i++) { bbI[i] = run; run += curI[i]; }
    bbI[NBK_] = run;
    rowU[U_] = E_;
    rowI[I_] = E_;
  }
}

// ---------------- 1c. Phase B ----------------
__global__ __launch_bounds__(256) void bucketB_kernel(
    const unsigned* __restrict__ bufU, const unsigned* __restrict__ bufI,
    const int* __restrict__ curU, const int* __restrict__ curI,
    const int* __restrict__ bbU, const int* __restrict__ bbI,
    int* __restrict__ rowU, int* __restrict__ rowI,
    int* __restrict__ csrU, int* __restrict__ csrI) {
  __shared__ int stage[CAP_];
  __shared__ int cntk[256], offk[256];
  __shared__ int wsum[4];
  int tid = threadIdx.x, b = blockIdx.x;
  int side = b >= NBK_;
  int bb = side ? b - NBK_ : b;
  const unsigned* src = (side ? bufI : bufU) + (size_t)bb * CAP_;
  int total = side ? curI[bb] : curU[bb];
  int gbase = side ? bbI[bb] : bbU[bb];
  int kpb   = side ? 128 : 256;
  int* rowptr = side ? rowI : rowU;
  int* csr    = side ? csrI : csrU;
  cntk[tid] = 0;
  __syncthreads();
  for (int r = tid; r < total; r += 256) atomicAdd(&cntk[src[r] >> 17], 1);
  __syncthreads();
  int lane = tid & 63, wv = tid >> 6;
  int cv = (tid < kpb) ? cntk[tid] : 0;
  int incl = waveInclScan(cv, lane);
  if (lane == 63) wsum[wv] = incl;
  __syncthreads();
  int wvoff = 0;
  for (int w = 0; w < wv; w++) wvoff += wsum[w];
  int excl = wvoff + incl - cv;
  if (tid < kpb) {
    offk[tid] = excl;
    rowptr[bb * kpb + tid] = gbase + excl;
  }
  __syncthreads();
  for (int r = tid; r < total; r += 256) {
    unsigned rec = src[r];
    int slot = atomicAdd(&offk[rec >> 17], 1);
    if (slot < CAP_) stage[slot] = (int)(rec & 0x1FFFFu);
  }
  __syncthreads();
  for (int s = tid; s < total; s += 256) csr[gbase + s] = stage[s];
}

// ---------------- 2. fused layer-1 aggregation (fp8 gather, bf16+fp8 out) -------
__global__ __launch_bounds__(256) void agg1_kernel(
    const unsigned char* __restrict__ ue8, const unsigned char* __restrict__ ie8,
    const int* __restrict__ rowU, const int* __restrict__ rowI,
    const int* __restrict__ csrU, const int* __restrict__ csrI,
    __hip_bfloat16* __restrict__ u1, __hip_bfloat16* __restrict__ i1,
    unsigned char* __restrict__ u18, unsigned char* __restrict__ i18) {
  int wv = threadIdx.x >> 6, lane = threadIdx.x & 63;
  int side = blockIdx.x >= I_ / 4;
  int blk = side ? blockIdx.x - I_ / 4 : blockIdx.x;
  int r = blk * 4 + wv;
  const int* row = side ? rowU : rowI;
  const int* csr = side ? csrU : csrI;
  const unsigned char* src = side ? ie8 : ue8;
  __hip_bfloat16* out = side ? u1 : i1;
  unsigned char* out8 = side ? u18 : i18;
  int s0 = row[r], s1 = row[r + 1];
  float acc = 0.f;
  int j = s0;
  for (; j + 4 <= s1; j += 4) {
    int a = csr[j], b = csr[j + 1], c = csr[j + 2], d = csr[j + 3];
    float va = fp8_dec(src[(size_t)a * 64 + lane]);
    float vb = fp8_dec(src[(size_t)b * 64 + lane]);
    float vc = fp8_dec(src[(size_t)c * 64 + lane]);
    float vd = fp8_dec(src[(size_t)d * 64 + lane]);
    acc += (va + vb) + (vc + vd);
  }
  for (; j < s1; j++) acc += fp8_dec(src[(size_t)csr[j] * 64 + lane]);
  float val = acc * ISCALE_E_ * frcp(fmaxf((float)(s1 - s0), 1.0f));
  size_t idx = (size_t)r * 64 + lane;
  out[idx] = __float2bfloat16(val);
  unsigned p = fp8_enc_pk(val * SCALE_1_, val * SCALE_1_);
  out8[idx] = (unsigned char)(p & 0xFF);
}

// ---------------- 3. fused layer-2 aggregation + attention (fp8 gather) ---------
__global__ __launch_bounds__(256) void agg2attn_kernel(
    const unsigned char* __restrict__ u18, const unsigned char* __restrict__ i18,
    const __hip_bfloat16* __restrict__ u1, const __hip_bfloat16* __restrict__ i1,
    const void* __restrict__ ue, const void* __restrict__ ie,
    const int* __restrict__ rowU, const int* __restrict__ rowI,
    const int* __restrict__ csrU, const int* __restrict__ csrI,
    const float* __restrict__ vecs, float* __restrict__ hu, float* __restrict__ hi,
    __hip_bfloat16* __restrict__ hub, __hip_bfloat16* __restrict__ hib,
    const float* __restrict__ flag) {
  int isf32 = *flag > 0.5f;
  int wv = threadIdx.x >> 6, lane = threadIdx.x & 63;
  int side = blockIdx.x >= I_ / 4;
  int blk = side ? blockIdx.x - I_ / 4 : blockIdx.x;
  int r = blk * 4 + wv;
  const int* row = side ? rowU : rowI;
  const int* csr = side ? csrU : csrI;
  const unsigned char* opp8 = side ? i18 : u18;
  const __hip_bfloat16* own1 = side ? u1 : i1;
  const void* base = side ? ue : ie;
  float* h = side ? hu : hi;
  __hip_bfloat16* hb = side ? hub : hib;
  int s0 = row[r], s1 = row[r + 1];
  float acc = 0.f;
  int j = s0;
  for (; j + 4 <= s1; j += 4) {
    int a = csr[j], b = csr[j + 1], c = csr[j + 2], d = csr[j + 3];
    float va = fp8_dec(opp8[(size_t)a * 64 + lane]);
    float vb = fp8_dec(opp8[(size_t)b * 64 + lane]);
    float vc = fp8_dec(opp8[(size_t)c * 64 + lane]);
    float vd = fp8_dec(opp8[(size_t)d * 64 + lane]);
    acc += (va + vb) + (vc + vd);
  }
  for (; j < s1; j++) acc += fp8_dec(opp8[(size_t)csr[j] * 64 + lane]);
  size_t idx = (size_t)r * 64 + lane;
  float t2 = acc * ISCALE_1_ * frcp(fmaxf((float)(s1 - s0), 1.0f));
  float t0 = ldf(base, idx, isf32);
  float t1 = b2f(own1[idx]);
  float w = vecs[lane];   // Wa
  float p0 = t0 * w, p1 = t1 * w, p2 = t2 * w;
  #pragma unroll
  for (int off = 32; off; off >>= 1) {
    p0 += __shfl_xor(p0, off, 64);
    p1 += __shfl_xor(p1, off, 64);
    p2 += __shfl_xor(p2, off, 64);
  }
  float m = fmaxf(p0, fmaxf(p1, p2));
  float e0 = __expf(p0 - m), e1 = __expf(p1 - m), e2 = __expf(p2 - m);
  float inv = 1.0f / (e0 + e1 + e2);
  float hv = (t0 * e0 + t1 * e1 + t2 * e2) * inv;
  h[idx] = hv;
  hb[idx] = __float2bfloat16(hv);
}

// ---------------- 5. contrastive loss: slim epilogue MFMA Gram ----------
constexpr int XS_ = 72;                   // f16 row stride (144 B)
constexpr float SC_  = 2.6857914f;        // sqrt(5*log2(e))
constexpr float EPS_ = 1e-6f;
constexpr float LN2_ = 0.6931471805599453f;
__global__ __launch_bounds__(1024) void contrast_kernel(
    const float* __restrict__ hu, const float* __restrict__ an,
    float* __restrict__ loss_acc) {
  __shared__ __align__(16) _Float16 Xh[512 * XS_];  // 72 KB
  __shared__ float iN[512];
  int tid = threadIdx.x;
  int c = blockIdx.x;

  if (tid < 512) {
    int row = tid & 255;
    const float* r1 = (tid < 256 ? hu : an) + ((size_t)c * CB_ + row) * 64;
    float4 a4[16];
    float s1 = 0.f;
    #pragma unroll
    for (int t = 0; t < 16; t++) {
      a4[t] = ((const float4*)r1)[t];
      s1 += a4[t].x * a4[t].x + a4[t].y * a4[t].y + a4[t].z * a4[t].z + a4[t].w * a4[t].w;
    }
    float inv = frcp(sqrtf(s1));
    iN[tid] = inv;
    float sc = inv * SC_;
    #pragma unroll
    for (int t = 0; t < 8; t++) {
      f16x8 v;
      v[0] = (_Float16)(a4[2*t].x * sc);   v[1] = (_Float16)(a4[2*t].y * sc);
      v[2] = (_Float16)(a4[2*t].z * sc);   v[3] = (_Float16)(a4[2*t].w * sc);
      v[4] = (_Float16)(a4[2*t+1].x * sc); v[5] = (_Float16)(a4[2*t+1].y * sc);
      v[6] = (_Float16)(a4[2*t+1].z * sc); v[7] = (_Float16)(a4[2*t+1].w * sc);
      *(f16x8*)&Xh[tid * XS_ + t * 8] = v;
    }
  }
  __syncthreads();

  int l = tid & 63, wv = tid >> 6;       // wv 0..15
  int n = l & 15, q = l >> 4;
  int rb = wv * 32;
  f16x8 A[2][2];
  #pragma unroll
  for (int t = 0; t < 2; t++) {
    A[t][0] = *(const f16x8*)&Xh[(rb + t * 16 + n) * XS_ + q * 8];
    A[t][1] = *(const f16x8*)&Xh[(rb + t * 16 + n) * XS_ + 32 + q * 8];
  }
  float eNiR[2][4];
  #pragma unroll
  for (int t = 0; t < 2; t++)
    #pragma unroll
    for (int r = 0; r < 4; r++)
      eNiR[t][r] = EPS_ * iN[rb + t * 16 + q * 4 + r];
  float sums[2][4] = {{0,0,0,0},{0,0,0,0}};
  float labs2[2] = {0, 0};
  int selfn = q * 4;
  const floatx4 zero = {0.f, 0.f, 0.f, 0.f};
  for (int ct = 0; ct < 32; ct++) {
    f16x8 B0 = *(const f16x8*)&Xh[(ct * 16 + n) * XS_ + q * 8];
    f16x8 B1 = *(const f16x8*)&Xh[(ct * 16 + n) * XS_ + 32 + q * 8];
    float iNj = iN[ct * 16 + n];
    #pragma unroll
    for (int t = 0; t < 2; t++) {
      floatx4 acc = __builtin_amdgcn_mfma_f32_16x16x32_f16(A[t][0], B0, zero, 0, 0, 0);
      acc = __builtin_amdgcn_mfma_f32_16x16x32_f16(A[t][1], B1, acc, 0, 0, 0);
      int rtg = wv * 2 + t;
      if (ct == (rtg ^ 16)) {
        #pragma unroll
        for (int r = 0; r < 4; r++) {
          float G = acc[r];
          float u = eNiR[t][r] * iNj;
          float s2 = __builtin_fmaf(G, -u, G);
          sums[t][r] += fexp2(s2);
          if (n == selfn + r) labs2[t] += s2;
        }
      } else if (ct == rtg) {
        #pragma unroll
        for (int r = 0; r < 4; r++) {
          float G = acc[r];
          float u = eNiR[t][r] * iNj;
          float s2 = __builtin_fmaf(G, -u, G);
          float e = (n == selfn + r) ? 0.f : fexp2(s2);
          sums[t][r] += e;
        }
      } else {
        #pragma unroll
        for (int r = 0; r < 4; r++) {
          float G = acc[r];
          float u = eNiR[t][r] * iNj;
          float s2 = __builtin_fmaf(G, -u, G);
          sums[t][r] += fexp2(s2);
        }
      }
    }
  }
  #pragma unroll
  for (int off = 1; off <= 8; off <<= 1) {
    #pragma unroll
    for (int t = 0; t < 2; t++) {
      #pragma unroll
      for (int r = 0; r < 4; r++) sums[t][r] += __shfl_xor(sums[t][r], off, 64);
      labs2[t] += __shfl_xor(labs2[t], off, 64);
    }
  }
  float part = 0.f;
  if (n == 0) {
    #pragma unroll
    for (int t = 0; t < 2; t++) {
      float lt = 0.f;
      #pragma unroll
      for (int r = 0; r < 4; r++) lt += __logf(sums[t][r]);
      part += lt - labs2[t] * LN2_;
    }
  }
  #pragma unroll
  for (int off = 1; off < 64; off <<= 1) part += __shfl_xor(part, off, 64);
  if (l == 0) atomicAdd(loss_acc, part);
}

// ---------------- 6. scores (bf16 gathers) ----------------
__global__ __launch_bounds__(256) void score_kernel(
    const __hip_bfloat16* __restrict__ hub, const __hip_bfloat16* __restrict__ hib,
    const int* __restrict__ pu, const int* __restrict__ pi,
    const int* __restrict__ nu, const int* __restrict__ ni,
    void* __restrict__ out, const float* __restrict__ flag) {
  int isf32 = *flag > 0.5f;
  int w = (blockIdx.x * 256 + threadIdx.x) >> 6;
  int lane = threadIdx.x & 63;
  int uu, ii;
  if (w < EP_) { uu = pu[w]; ii = pi[w]; }
  else         { uu = nu[w - EP_]; ii = ni[w - EP_]; }
  float p = b2f(hub[(size_t)uu * 64 + lane]) * b2f(hib[(size_t)ii * 64 + lane]);
  #pragma unroll
  for (int off = 32; off; off >>= 1) p += __shfl_xor(p, off, 64);
  if (lane == 0) {
    if (isf32) ((float*)out)[w] = p;
    else       ((__hip_bfloat16*)out)[w] = __float2bfloat16(p);
  }
}

__global__ void finalize_kernel(const float* __restrict__ loss_acc,
                                void* __restrict__ out,
                                const float* __restrict__ flag) {
  float v = loss_acc[0] * (1.0f / (float)(2 * CB_ * NCHUNK_));
  if (*flag > 0.5f) ((float*)out)[2 * EP_] = v;
  else              ((__hip_bfloat16*)out)[2 * EP_] = __float2bfloat16(v);
}

// ---------------- launch ----------------
extern "C" void kernel_launch(void* const* d_in, const int* in_sizes, int n_in,
                              void* d_out, int out_size, void* d_ws, size_t ws_size,
                              hipStream_t stream) {
  const void* ue  = d_in[0];
  const void* ie  = d_in[1];
  const void* W   = d_in[2];
  const void* a   = d_in[3];
  const void* WU  = d_in[4];
  const void* aU  = d_in[5];
  const void* cw  = d_in[6];
  const int* rs  = (const int*)d_in[7];
  const int* rd  = (const int*)d_in[8];
  const int* pu  = (const int*)d_in[9];
  const int* pi  = (const int*)d_in[10];
  const int* nu  = (const int*)d_in[11];
  const int* ni  = (const int*)d_in[12];
  const int* nbr = (const int*)d_in[13];

  float* wsf  = (float*)d_ws;
  int*   wsi  = (int*)d_ws;
  float* loss = wsf + OFF_LOSS;
  float* flag = wsf + OFF_FLAG;
  int* curU   = wsi + OFF_CURU;
  int* curI   = wsi + OFF_CURI;
  float* vecs = wsf + OFF_VEC;
  int* bbU    = wsi + OFF_BBU;
  int* bbI    = wsi + OFF_BBI;
  int* rowU   = wsi + OFF_ROWU;
  int* rowI   = wsi + OFF_ROWI;
  int* csrU   = wsi + OFF_CSRU;
  int* csrI   = wsi + OFF_CSRI;
  __hip_bfloat16* u1 = (__hip_bfloat16*)(wsf + OFF_U1);
  __hip_bfloat16* i1 = (__hip_bfloat16*)(wsf + OFF_I1);
  float* hu   = wsf + OFF_HU;
  float* hi   = wsf + OFF_HI;
  float* anc  = wsf + OFF_ANC;
  unsigned char* ue8 = (unsigned char*)(wsf + OFF_UE8);
  unsigned char* ie8 = (unsigned char*)(wsf + OFF_IE8);
  unsigned char* u18 = (unsigned char*)(wsf + OFF_U18);
  unsigned char* i18 = (unsigned char*)(wsf + OFF_I18);
  __hip_bfloat16* hub = (__hip_bfloat16*)(wsf + OFF_HUB);
  __hip_bfloat16* hib = (__hip_bfloat16*)(wsf + OFF_HIB);
  unsigned* bufU = (unsigned*)(wsf + OFF_HU);
  unsigned* bufI = (unsigned*)(wsf + OFF_HI);

  hipMemsetAsync(d_ws, 0, MEMSET_BYTES, stream);
  prep_kernel<<<1, 64, 0, stream>>>((const unsigned short*)ue, W, a, WU, aU, vecs, flag);

  // fp8 tables (must precede fusedA's anchor gathers)
  convert_kernel<<<NCVT_, 256, 0, stream>>>(ue, ie, ue8, ie8, flag);

  // fused: CSR Phase A + anchor (fp8 gathers)
  fusedA_kernel<<<NBA_ + NANC_, 256, 0, stream>>>(
      rs, rd, bufU, bufI, curU, curI, ue8, WU, cw, vecs, nbr, anc, flag);
  scanBuckets_kernel<<<1, 64, 0, stream>>>(curU, curI, bbU, bbI, rowU, rowI);
  bucketB_kernel<<<2 * NBK_, 256, 0, stream>>>(bufU, bufI, curU, curI, bbU, bbI,
                                               rowU, rowI, csrU, csrI);

  // fused layer-1 aggregation (fp8 gather, both sides)
  agg1_kernel<<<(I_ + U_) / 4, 256, 0, stream>>>(ue8, ie8, rowU, rowI, csrU, csrI,
                                                 u1, i1, u18, i18);
  // fused layer-2 aggregation + attention (fp8 gather; emits f32 + bf16 h)
  agg2attn_kernel<<<(I_ + U_) / 4, 256, 0, stream>>>(u18, i18, u1, i1, ue, ie,
                                                     rowU, rowI, csrU, csrI,
                                                     vecs, hu, hi, hub, hib, flag);

  // contrastive loss
  contrast_kernel<<<NCHUNK_, 1024, 0, stream>>>(hu, anc, loss);

  // scores (bf16 gathers)
  score_kernel<<<(2 * EP_ * 64) / 256, 256, 0, stream>>>(hub, hib, pu, pi, nu, ni, d_out, flag);
  finalize_kernel<<<1, 1, 0, stream>>>(loss, d_out, flag);
}